// Round 5
// baseline (6195.782 us; speedup 1.0000x reference)
//
#include <hip/hip_runtime.h>

// Per-channel LSTM (input_size=1) + per-channel Linear(H,1), fully fused.
// B=512, T=1024, C=64, H=128.
// Round 5: occupancy is the bottleneck (1 block/CU since R1; gfx950 unified
// reg file -> residency counts arch VGPR + AGPR; R4 was 116+16=132, just
// over the 128/wave line for 2 blocks/CU). Shave registers under 128 total:
//  - x staged via ping-pong LDS (64 floats/step loaded by 64 threads),
//    killing the 16 xv prefetch VGPRs and 16 redundant scalar global
//    loads/lane/step.
//  - tanh(c) back to per-cell rcp (drops cn/og/Dq cross-row buffers ~10
//    regs; +0.75 trans/cell which R4 proved costs ~nothing).
// Gate activations keep the merged single-rcp form. Structure otherwise R4.

typedef _Float16 half8 __attribute__((ext_vector_type(8)));
typedef float floatx4 __attribute__((ext_vector_type(4)));

#define LOG2E 1.44269504088896340736f

__global__ __launch_bounds__(512, 2) void lstm_fused(
    const float* __restrict__ x,    // [B,T,C]
    const float* __restrict__ Wih,  // [C,4H]
    const float* __restrict__ Whh,  // [C,4H,H]
    const float* __restrict__ bih,  // [C,4H]
    const float* __restrict__ bhh,  // [C,4H]
    const float* __restrict__ Wfc,  // [C,H]
    const float* __restrict__ bfc,  // [C]
    float* __restrict__ out)        // [B,C]
{
    constexpr int T = 1024, C = 64, H = 128, G = 512;
    constexpr int TC = T * C;

    // Two h buffers: [4 rowtiles][4 ksteps][64 chunks][8 f16] = 16 KB each.
    __shared__ _Float16 hbuf[2][8192];
    // Ping-pong x stage: 64 rows' x values for the current / next step.
    __shared__ float xstage[2][64];

    const int bid = blockIdx.x;
    const int ch  = bid & 63;          // channel
    const int b0  = (bid >> 6) << 6;   // batch tile base: 0,64,...,448

    const int tid = threadIdx.x;
    const int w   = tid >> 6;          // wave 0..7 -> hidden slice [w*16, w*16+16)
    const int l   = tid & 63;
    const int q   = l >> 4;            // quad
    const int li  = l & 15;

    // ---- per-lane constants: W_ih, bias, W_hh fragments in registers ----
    float wihr[4], bias[4];
    half8 Wf[4][4];
#pragma unroll
    for (int ct = 0; ct < 4; ++ct) {
        const float sc = (ct == 2) ? 2.0f * LOG2E : LOG2E;  // gate order i,f,g,o
        const int col = ct * H + w * 16 + li;
        wihr[ct] = Wih[ch * G + col] * sc;
        bias[ct] = (bih[ch * G + col] + bhh[ch * G + col]) * sc;
#pragma unroll
        for (int ks = 0; ks < 4; ++ks) {
            const float* wp = &Whh[((size_t)(ch * G + col)) * H + ks * 32 + q * 8];
            half8 hv;
#pragma unroll
            for (int j = 0; j < 8; ++j) hv[j] = (_Float16)(wp[j] * sc);
            Wf[ct][ks] = hv;
        }
    }

    // zero t=0 read buffer (h0 = 0)
    for (int i = tid; i < 8192; i += 512) hbuf[0][i] = (_Float16)0.0f;

    // x row pointer for the stage loader (threads 0..63 = one batch row each)
    const float* xrow = x + (size_t)(b0 + (tid & 63)) * TC + ch;
    if (tid < 64) xstage[0][tid] = xrow[0];  // t = 0

    // cell state (fp32 registers): 4 rowtiles x 4 rows
    float cst[4][4];
#pragma unroll
    for (int rt = 0; rt < 4; ++rt)
#pragma unroll
        for (int r = 0; r < 4; ++r) cst[rt][r] = 0.0f;

    // ---- h layout with XOR bank swizzle ----
    // value (batch row m in tile, hidden hh): ks=hh>>5, qq=(hh&31)>>3, j=hh&7
    // chunk c = qq*16 + (m ^ (qq&3)); element = (rt*4+ks)*512 + c*8 + j
    const int ks_w = w >> 1;
    const int qq_w = ((w & 1) << 1) + (li >> 3);
    const int j_w  = li & 7;
    const int rxor = qq_w & 3;
    int wel[4];
#pragma unroll
    for (int r = 0; r < 4; ++r)
        wel[r] = ks_w * 512 + (qq_w * 16 + q * 4 + (r ^ rxor)) * 8 + j_w;
    // read: lane l wants chunk (qq=q, m=li) -> c = q*16 + (li ^ (q&3))
    const int rdoff = (q * 16 + (li ^ (q & 3))) * 8;

    __syncthreads();

    auto step = [&](const _Float16* __restrict__ rb, _Float16* __restrict__ wb,
                    const float* __restrict__ xcur, float* __restrict__ xnxt,
                    int tn) {
        // prefetch next step's x early (global latency hides behind compute)
        float xpre;
        if (tid < 64) xpre = xrow[tn * C];

#pragma unroll
        for (int rt = 0; rt < 4; ++rt) {
            // x for this rowtile's 4 rows: one b128 broadcast read
            const floatx4 xq = *(const floatx4*)&xcur[rt * 16 + q * 4];

            // init acc with x*W_ih + bias (one fma each)
            floatx4 acc[4];
#pragma unroll
            for (int ct = 0; ct < 4; ++ct)
#pragma unroll
                for (int r = 0; r < 4; ++r)
                    acc[ct][r] = fmaf(xq[r], wihr[ct], bias[ct]);

            // one A-fragment live at a time: ds_read_b128 then its 4 MFMAs
#pragma unroll
            for (int ks = 0; ks < 4; ++ks) {
                const half8 a = *(const half8*)&rb[(rt * 4 + ks) * 512 + rdoff];
#pragma unroll
                for (int ct = 0; ct < 4; ++ct)
                    acc[ct] = __builtin_amdgcn_mfma_f32_16x16x32_f16(a, Wf[ct][ks], acc[ct], 0, 0, 0);
            }

            // activations: one rcp for all 4 gate denominators, one rcp for
            // tanh(c). Preacts prescaled by log2e (g by 2*log2e).
            // |preact| <= ~18 (scaled) -> product <= ~2^87, no overflow.
#pragma unroll
            for (int r = 0; r < 4; ++r) {
                const float u  = __builtin_amdgcn_exp2f(-acc[0][r]);
                const float v  = __builtin_amdgcn_exp2f(-acc[1][r]);
                const float p  = __builtin_amdgcn_exp2f(acc[2][r]);
                const float wq = __builtin_amdgcn_exp2f(-acc[3][r]);
                const float Du = 1.0f + u, Dv = 1.0f + v;
                const float Dp = 1.0f + p, Dw = 1.0f + wq;
                const float A  = Du * Dv, Bq = Dp * Dw;
                const float R  = __builtin_amdgcn_rcpf(A * Bq);
                const float RA = R * Bq;                      // 1/(Du*Dv)
                const float RB = R * A;                       // 1/(Dp*Dw)
                const float ig = Dv * RA;                     // sigmoid(i)
                const float fg = Du * RA;                     // sigmoid(f)
                const float tg = fmaf(-2.0f, Dw * RB, 1.0f);  // tanh(g)
                const float og = Dp * RB;                     // sigmoid(o)
                const float cn = fmaf(fg, cst[rt][r], ig * tg);
                cst[rt][r] = cn;
                // tanh(cn): clamp exp2 arg to +-29 (tanh saturates to 1.0f)
                const float tq = __builtin_amdgcn_fmed3f(
                    cn * (2.0f * LOG2E), -29.0f, 29.0f);
                const float hq = fmaf(-2.0f,
                    __builtin_amdgcn_rcpf(1.0f + __builtin_amdgcn_exp2f(tq)), 1.0f);
                wb[rt * 2048 + wel[r]] = (_Float16)(og * hq);
            }
        }

        // publish next step's x, then the per-step barrier
        if (tid < 64) xnxt[tid] = xpre;
        __syncthreads();
    };

    for (int t = 0; t < T; t += 2) {
        step(hbuf[0], hbuf[1], xstage[0], xstage[1], t + 1);
        step(hbuf[1], hbuf[0], xstage[1], xstage[0], (t + 2 < T) ? t + 2 : T - 1);
    }

    // ---- epilogue: out[b0+row, ch] = h_final . Wfc[ch] + bfc[ch] ----
    // T even -> final h is in hbuf[0]; last __syncthreads already done.
    if (tid < 64) {
        const int row = tid;
        const int rt = row >> 4, m = row & 15;
        float s = bfc[ch];
#pragma unroll
        for (int hh = 0; hh < H; ++hh) {
            const int ks = hh >> 5, qq = (hh & 31) >> 3, j = hh & 7;
            const int c = qq * 16 + (m ^ (qq & 3));
            s += (float)hbuf[0][(rt * 4 + ks) * 512 + c * 8 + j] * Wfc[ch * H + hh];
        }
        out[(size_t)(b0 + row) * C + ch] = s;
    }
}

extern "C" void kernel_launch(void* const* d_in, const int* in_sizes, int n_in,
                              void* d_out, int out_size, void* d_ws, size_t ws_size,
                              hipStream_t stream) {
    const float* x   = (const float*)d_in[0];
    const float* Wih = (const float*)d_in[1];
    const float* Whh = (const float*)d_in[2];
    const float* bih = (const float*)d_in[3];
    const float* bhh = (const float*)d_in[4];
    const float* Wfc = (const float*)d_in[5];
    const float* bfc = (const float*)d_in[6];
    float* out = (float*)d_out;

    lstm_fused<<<512, 512, 0, stream>>>(x, Wih, Whh, bih, bhh, Wfc, bfc, out);
}

// Round 6
// 6097.564 us; speedup vs baseline: 1.0161x; 1.0161x over previous
//
#include <hip/hip_runtime.h>

// Per-channel LSTM (input_size=1) + per-channel Linear(H,1), fully fused.
// B=512, T=1024, C=64, H=128.
// Round 6: co-residency model fitted to R1-R5:
//   2 blocks/CU require  (a) total regs/wave (arch+AGPR) < 128  AND
//                        (b) aggregate LDS <= 64 KiB (2 x 32768 fits exactly;
//                            R5's +512B xstage broke it -> 1 block/CU).
// So: R5's slim activation path (merged gate rcp, per-cell tanh rcp)
//   + R4's register-resident x prefetch (16 VGPR, ~96 arch total)
//   + LDS = hbuf only = 32768 exactly.

typedef _Float16 half8 __attribute__((ext_vector_type(8)));
typedef float floatx4 __attribute__((ext_vector_type(4)));

#define LOG2E 1.44269504088896340736f

__global__ __launch_bounds__(512, 2) void lstm_fused(
    const float* __restrict__ x,    // [B,T,C]
    const float* __restrict__ Wih,  // [C,4H]
    const float* __restrict__ Whh,  // [C,4H,H]
    const float* __restrict__ bih,  // [C,4H]
    const float* __restrict__ bhh,  // [C,4H]
    const float* __restrict__ Wfc,  // [C,H]
    const float* __restrict__ bfc,  // [C]
    float* __restrict__ out)        // [B,C]
{
    constexpr int T = 1024, C = 64, H = 128, G = 512;
    constexpr int TC = T * C;

    // Two h buffers: [4 rowtiles][4 ksteps][64 chunks][8 f16] = 16 KB each.
    // TOTAL LDS = 32768 exactly — do not add a single byte (see header).
    __shared__ _Float16 hbuf[2][8192];

    const int bid = blockIdx.x;
    const int ch  = bid & 63;          // channel
    const int b0  = (bid >> 6) << 6;   // batch tile base: 0,64,...,448

    const int tid = threadIdx.x;
    const int w   = tid >> 6;          // wave 0..7 -> hidden slice [w*16, w*16+16)
    const int l   = tid & 63;
    const int q   = l >> 4;            // quad
    const int li  = l & 15;

    // ---- per-lane constants: W_ih, bias, W_hh fragments in registers ----
    float wihr[4], bias[4];
    half8 Wf[4][4];
#pragma unroll
    for (int ct = 0; ct < 4; ++ct) {
        const float sc = (ct == 2) ? 2.0f * LOG2E : LOG2E;  // gate order i,f,g,o
        const int col = ct * H + w * 16 + li;
        wihr[ct] = Wih[ch * G + col] * sc;
        bias[ct] = (bih[ch * G + col] + bhh[ch * G + col]) * sc;
#pragma unroll
        for (int ks = 0; ks < 4; ++ks) {
            const float* wp = &Whh[((size_t)(ch * G + col)) * H + ks * 32 + q * 8];
            half8 hv;
#pragma unroll
            for (int j = 0; j < 8; ++j) hv[j] = (_Float16)(wp[j] * sc);
            Wf[ct][ks] = hv;
        }
    }

    // zero t=0 read buffer (h0 = 0)
    for (int i = tid; i < 8192; i += 512) hbuf[0][i] = (_Float16)0.0f;

    // cell state (fp32 registers): 4 rowtiles x 4 rows
    float cst[4][4];
#pragma unroll
    for (int rt = 0; rt < 4; ++rt)
#pragma unroll
        for (int r = 0; r < 4; ++r) cst[rt][r] = 0.0f;

    // ---- h layout with XOR bank swizzle ----
    // value (batch row m in tile, hidden hh): ks=hh>>5, qq=(hh&31)>>3, j=hh&7
    // chunk c = qq*16 + (m ^ (qq&3)); element = (rt*4+ks)*512 + c*8 + j
    const int ks_w = w >> 1;
    const int qq_w = ((w & 1) << 1) + (li >> 3);
    const int j_w  = li & 7;
    const int rxor = qq_w & 3;
    int wel[4];
#pragma unroll
    for (int r = 0; r < 4; ++r)
        wel[r] = ks_w * 512 + (qq_w * 16 + q * 4 + (r ^ rxor)) * 8 + j_w;
    // read: lane l wants chunk (qq=q, m=li) -> c = q*16 + (li ^ (q&3))
    const int rdoff = (q * 16 + (li ^ (q & 3))) * 8;

    // ---- x addressing: uniform base pointer + per-lane 32-bit offset ----
    const float* xb = x + ch;
    const int rb0 = (b0 + q * 4) * TC;  // per-lane element offset base

    float xv[4][4];
#pragma unroll
    for (int rt = 0; rt < 4; ++rt)
#pragma unroll
        for (int r = 0; r < 4; ++r)
            xv[rt][r] = xb[rb0 + (rt * 16 + r) * TC];  // t = 0

    const float* xnp   = xb + C;              // next-step base (t=1)
    const float* xlast = xb + (T - 1) * C;

    __syncthreads();

    auto step = [&](const _Float16* __restrict__ rb, _Float16* __restrict__ wb) {
#pragma unroll
        for (int rt = 0; rt < 4; ++rt) {
            // init acc with x*W_ih + bias (one fma each)
            floatx4 acc[4];
#pragma unroll
            for (int ct = 0; ct < 4; ++ct)
#pragma unroll
                for (int r = 0; r < 4; ++r)
                    acc[ct][r] = fmaf(xv[rt][r], wihr[ct], bias[ct]);

            // one A-fragment live at a time: ds_read_b128 then its 4 MFMAs
#pragma unroll
            for (int ks = 0; ks < 4; ++ks) {
                const half8 a = *(const half8*)&rb[(rt * 4 + ks) * 512 + rdoff];
#pragma unroll
                for (int ct = 0; ct < 4; ++ct)
                    acc[ct] = __builtin_amdgcn_mfma_f32_16x16x32_f16(a, Wf[ct][ks], acc[ct], 0, 0, 0);
            }

            // activations: one rcp for all 4 gate denominators, one rcp for
            // tanh(c). Preacts prescaled by log2e (g by 2*log2e).
#pragma unroll
            for (int r = 0; r < 4; ++r) {
                const float u  = __builtin_amdgcn_exp2f(-acc[0][r]);
                const float v  = __builtin_amdgcn_exp2f(-acc[1][r]);
                const float p  = __builtin_amdgcn_exp2f(acc[2][r]);
                const float wq = __builtin_amdgcn_exp2f(-acc[3][r]);
                const float Du = 1.0f + u, Dv = 1.0f + v;
                const float Dp = 1.0f + p, Dw = 1.0f + wq;
                const float A  = Du * Dv, Bq = Dp * Dw;
                const float R  = __builtin_amdgcn_rcpf(A * Bq);
                const float RA = R * Bq;                      // 1/(Du*Dv)
                const float RB = R * A;                       // 1/(Dp*Dw)
                const float ig = Dv * RA;                     // sigmoid(i)
                const float fg = Du * RA;                     // sigmoid(f)
                const float tg = fmaf(-2.0f, Dw * RB, 1.0f);  // tanh(g)
                const float og = Dp * RB;                     // sigmoid(o)
                const float cn = fmaf(fg, cst[rt][r], ig * tg);
                cst[rt][r] = cn;
                // tanh(cn): clamp exp2 arg to +-29 (tanh saturates to 1.0f)
                const float tq = __builtin_amdgcn_fmed3f(
                    cn * (2.0f * LOG2E), -29.0f, 29.0f);
                const float hq = fmaf(-2.0f,
                    __builtin_amdgcn_rcpf(1.0f + __builtin_amdgcn_exp2f(tq)), 1.0f);
                wb[rt * 2048 + wel[r]] = (_Float16)(og * hq);
            }
        }

        // reload xv for the NEXT step (same registers -> prefetch across barrier)
#pragma unroll
        for (int rt = 0; rt < 4; ++rt)
#pragma unroll
            for (int r = 0; r < 4; ++r)
                xv[rt][r] = xnp[rb0 + (rt * 16 + r) * TC];

        __syncthreads();
    };

    for (int t = 0; t < T; t += 2) {
        step(hbuf[0], hbuf[1]);
        xnp = (xnp == xlast) ? xnp : xnp + C;
        step(hbuf[1], hbuf[0]);
        xnp = (xnp == xlast) ? xnp : xnp + C;
    }

    // ---- epilogue: out[b0+row, ch] = h_final . Wfc[ch] + bfc[ch] ----
    // T even -> final h is in hbuf[0]; last __syncthreads already done.
    if (tid < 64) {
        const int row = tid;
        const int rt = row >> 4, m = row & 15;
        float s = bfc[ch];
#pragma unroll
        for (int hh = 0; hh < H; ++hh) {
            const int ks = hh >> 5, qq = (hh & 31) >> 3, j = hh & 7;
            const int c = qq * 16 + (m ^ (qq & 3));
            s += (float)hbuf[0][(rt * 4 + ks) * 512 + c * 8 + j] * Wfc[ch * H + hh];
        }
        out[(size_t)(b0 + row) * C + ch] = s;
    }
}

extern "C" void kernel_launch(void* const* d_in, const int* in_sizes, int n_in,
                              void* d_out, int out_size, void* d_ws, size_t ws_size,
                              hipStream_t stream) {
    const float* x   = (const float*)d_in[0];
    const float* Wih = (const float*)d_in[1];
    const float* Whh = (const float*)d_in[2];
    const float* bih = (const float*)d_in[3];
    const float* bhh = (const float*)d_in[4];
    const float* Wfc = (const float*)d_in[5];
    const float* bfc = (const float*)d_in[6];
    float* out = (float*)d_out;

    lstm_fused<<<512, 512, 0, stream>>>(x, Wih, Whh, bih, bhh, Wfc, bfc, out);
}